// Round 12
// baseline (209.369 us; speedup 1.0000x reference)
//
#include <hip/hip_runtime.h>
#include <math.h>

// 2D IDCT 4096x4096 — three kernels, host-precomputed tables.
// Tables: computed once on host (double precision), memcpyAsync'd to d_ws
//         (kills the init kernel + one ~14us launch boundary).
// colA: Z-build + 32-pt FFT as in-wave DIT (lane l <-> l+32 = k2 parity);
//       writes T1 in [n2][k1][c] layout (k1-contiguous).
// colB: 64-pt FFT as in-wave DIT over k1; reads T1 as 64 CONSECUTIVE rows
//       per block (dense 1MB window) instead of a stride-32-row comb.
// rows: in-place LDS Stockham radix-8/8/8/4, float4 staged I/O.
// No cooperative launch: proven flaky under graph capture (rounds 9-11).

#define TT 256

constexpr float W64R[32] = {
    1.0f, 0.995184726672197f, 0.980785280403230f, 0.956940335732209f,
    0.923879532511287f, 0.881921264348355f, 0.831469612302545f, 0.773010453362737f,
    0.707106781186548f, 0.634393284163645f, 0.555570233019602f, 0.471396736825998f,
    0.382683432365090f, 0.290284677254462f, 0.195090322016128f, 0.0980171403295606f,
    0.0f, -0.0980171403295606f, -0.195090322016128f, -0.290284677254462f,
    -0.382683432365090f, -0.471396736825998f, -0.555570233019602f, -0.634393284163645f,
    -0.707106781186548f, -0.773010453362737f, -0.831469612302545f, -0.881921264348355f,
    -0.923879532511287f, -0.956940335732209f, -0.980785280403230f, -0.995184726672197f};
constexpr float W64I[32] = {
    0.0f, 0.0980171403295606f, 0.195090322016128f, 0.290284677254462f,
    0.382683432365090f, 0.471396736825998f, 0.555570233019602f, 0.634393284163645f,
    0.707106781186548f, 0.773010453362737f, 0.831469612302545f, 0.881921264348355f,
    0.923879532511287f, 0.956940335732209f, 0.980785280403230f, 0.995184726672197f,
    1.0f, 0.995184726672197f, 0.980785280403230f, 0.956940335732209f,
    0.923879532511287f, 0.881921264348355f, 0.831469612302545f, 0.773010453362737f,
    0.707106781186548f, 0.634393284163645f, 0.555570233019602f, 0.471396736825998f,
    0.382683432365090f, 0.290284677254462f, 0.195090322016128f, 0.0980171403295606f};

__device__ __forceinline__ constexpr int brev(int x, int bits) {
    int r = 0;
    for (int i = 0; i < bits; ++i) { r = (r << 1) | (x & 1); x >>= 1; }
    return r;
}

template <int NP>
__device__ __forceinline__ void fft_dif(float* re, float* im) {
#pragma unroll
    for (int h = NP / 2; h >= 1; h >>= 1) {
#pragma unroll
        for (int b = 0; b < NP; b += 2 * h) {
#pragma unroll
            for (int k = 0; k < h; ++k) {
                float ur = re[b + k], ui = im[b + k];
                float vr = re[b + k + h], vi = im[b + k + h];
                float dr = ur - vr, di = ui - vi;
                re[b + k] = ur + vr;
                im[b + k] = ui + vi;
                float wr = W64R[k * (32 / h)], wi = W64I[k * (32 / h)];
                re[b + k + h] = dr * wr - di * wi;
                im[b + k + h] = dr * wi + di * wr;
            }
        }
    }
}

#define C_SQ2 0.70710678118654752440f
__device__ __forceinline__ void radix8(const float* ar, const float* ai,
                                       float* tr, float* ti) {
    float s04r = ar[0] + ar[4], s04i = ai[0] + ai[4];
    float d04r = ar[0] - ar[4], d04i = ai[0] - ai[4];
    float s26r = ar[2] + ar[6], s26i = ai[2] + ai[6];
    float d26r = ar[2] - ar[6], d26i = ai[2] - ai[6];
    float E0r = s04r + s26r, E0i = s04i + s26i;
    float E1r = d04r - d26i, E1i = d04i + d26r;
    float E2r = s04r - s26r, E2i = s04i - s26i;
    float E3r = d04r + d26i, E3i = d04i - d26r;
    float s15r = ar[1] + ar[5], s15i = ai[1] + ai[5];
    float d15r = ar[1] - ar[5], d15i = ai[1] - ai[5];
    float s37r = ar[3] + ar[7], s37i = ai[3] + ai[7];
    float d37r = ar[3] - ar[7], d37i = ai[3] - ai[7];
    float O0r = s15r + s37r, O0i = s15i + s37i;
    float O1r = d15r - d37i, O1i = d15i + d37r;
    float O2r = s15r - s37r, O2i = s15i - s37i;
    float O3r = d15r + d37i, O3i = d15i - d37r;
    float W1r = C_SQ2 * (O1r - O1i), W1i = C_SQ2 * (O1r + O1i);
    float W2r = -O2i, W2i = O2r;
    float W3r = -C_SQ2 * (O3r + O3i), W3i = C_SQ2 * (O3r - O3i);
    tr[0] = E0r + O0r; ti[0] = E0i + O0i;
    tr[4] = E0r - O0r; ti[4] = E0i - O0i;
    tr[1] = E1r + W1r; ti[1] = E1i + W1i;
    tr[5] = E1r - W1r; ti[5] = E1i - W1i;
    tr[2] = E2r + W2r; ti[2] = E2i + W2i;
    tr[6] = E2r - W2r; ti[6] = E2i - W2i;
    tr[3] = E3r + W3r; ti[3] = E3i + W3i;
    tr[7] = E3r - W3r; ti[7] = E3i - W3i;
}

// ---- column pass A: 32-pt FFT as in-wave DIT; T1 stored [n2][k1][c] -------
// grid 2048 x 256: vb -> bx (c-tile, &127), by (>>7); k1 = by*4 + (t>>6).
__global__ __launch_bounds__(TT) void col_a_kernel(
    const float* __restrict__ x, const float4* __restrict__ cAC,
    const float2* __restrict__ tw2048, float2* __restrict__ T1) {
    const int vb = blockIdx.x;
    const int bx = vb & 127, by = vb >> 7;
    const int t = threadIdx.x;
    const int l = t & 63;
    const int ty = t >> 6;
    const int par = l >> 5;                  // k2 parity of this lane
    const int c = bx * 32 + (l & 31);
    const int k1 = by * 4 + ty;              // [0,64)
    float fr[16], fi[16];
#pragma unroll
    for (int a = 0; a < 16; ++a) {
        int k = k1 + 64 * (2 * a + par);
        float xa = x[(size_t)k * 4096 + c];
        float xb = x[(size_t)((4096 - k) & 4095) * 4096 + c];
        float xc = x[(size_t)(2048 + k) * 4096 + c];
        float xd = x[(size_t)(2048 - k) * 4096 + c];
        float4 P = cAC[k];                   // (Ar, Ai, Cr, Ci)
        float bs = (k == 0) ? 0.0f : 1.0f;   // B = bs*(Ai,-Ar), D = (Ci,-Cr)
        fr[a] = P.x * xa + bs * P.y * xb + P.z * xc + P.w * xd;
        fi[a] = P.y * xa - bs * P.x * xb + P.w * xc - P.z * xd;
    }
    fft_dif<16>(fr, fi);                     // E (par=0) or O (par=1)
    const float sgn = par ? -1.0f : 1.0f;
#pragma unroll
    for (int j = 0; j < 16; ++j) {
        int n = brev(j, 4);
        float wr = par ? W64R[2 * n] : 1.0f; // W32^n on odd branch
        float wi = par ? W64I[2 * n] : 0.0f;
        float vr = fr[j] * wr - fi[j] * wi;
        float vi = fr[j] * wi + fi[j] * wr;
        float orr = __shfl_xor(vr, 32, 64);
        float oii = __shfl_xor(vi, 32, 64);
        float zr = orr + sgn * vr;           // lower: E+WO ; upper: E-WO
        float zi = oii + sgn * vi;
        int n2 = par ? (n + 16) : n;
        float2 w2 = tw2048[k1 * n2];
        float2 o = make_float2(zr * w2.x - zi * w2.y,
                               zr * w2.y + zi * w2.x);
        T1[(size_t)(n2 * 64 + k1) * 4096 + c] = o;   // [n2][k1][c]
    }
}

// ---- column pass B: 64-pt FFT as in-wave DIT over k1 ----------------------
// T1 [n2][k1][c]: block reads 64 CONSECUTIVE rows (1 MB window, dense).
// grid 1024 x 256: vb -> bx (&127), by (>>7); n2 = by*4 + (t>>6).
__global__ __launch_bounds__(TT, 1) void col_b_kernel(
    const float2* __restrict__ T1, float* __restrict__ out) {
    const int vb = blockIdx.x;
    const int bx = vb & 127, by = vb >> 7;
    const int t = threadIdx.x;
    const int wv = t >> 6;
    const int l = t & 63;
    const int par = l >> 5;                  // k1 parity of this lane
    const int c = bx * 32 + (l & 31);
    const int n2 = by * 4 + wv;
    float fr[32], fi[32];
#pragma unroll
    for (int a = 0; a < 32; ++a) {
        int k1 = 2 * a + par;
        float2 v = T1[(size_t)(n2 * 64 + k1) * 4096 + c];
        fr[a] = v.x; fi[a] = v.y;
    }
    fft_dif<32>(fr, fi);                     // E (par=0) or O (par=1)
    const float sgn = par ? -1.0f : 1.0f;
#pragma unroll
    for (int j = 0; j < 32; ++j) {
        int n = brev(j, 5);
        float wr = par ? W64R[n] : 1.0f;     // W64^n on odd branch
        float wi = par ? W64I[n] : 0.0f;
        float vr = fr[j] * wr - fi[j] * wi;
        float vi = fr[j] * wi + fi[j] * wr;
        float orr = __shfl_xor(vr, 32, 64);
        float oii = __shfl_xor(vi, 32, 64);
        float zr = orr + sgn * vr;
        float zi = oii + sgn * vi;
        int n1 = par ? (n + 32) : n;
        int m = 32 * n1 + n2;
        int r_re = (n1 < 32) ? 4 * m     : 8191 - 4 * m;
        int r_im = (n1 < 32) ? 4 * m + 2 : 8189 - 4 * m;
        out[(size_t)r_re * 4096 + c] = zr;
        out[(size_t)r_im * 4096 + c] = zi;
    }
}

// ---- row pass: in-place per-row IDCT, float4 staged I/O -------------------
__global__ __launch_bounds__(TT) void idct_rows_kernel(
    const float2* __restrict__ ca, const float2* __restrict__ cb,
    const float2* __restrict__ cc, const float2* __restrict__ cd,
    const float2* __restrict__ tw2048, float* __restrict__ io) {
    __shared__ float pool[8576];
    float* b0r = pool;
    float* b0i = pool + 2112;
    float* b1r = pool + 4224;
    float* b1i = pool + 6400;
    float* stg = pool + 4224;   // overlays b1 (free until stage B)
    const int t = threadIdx.x;
    float* __restrict__ xr = io + (size_t)blockIdx.x * 4096;

#pragma unroll
    for (int u = 0; u < 4; ++u) {
        int idx = t + 256 * u;
        float4 v = ((const float4*)xr)[idx];
        *(float4*)&stg[4 * idx] = v;
    }
    __syncthreads();

    float zr[8], zi[8], tr[8], ti[8];
#pragma unroll
    for (int p = 0; p < 8; ++p) {
        int k = t + 256 * p;
        float xa = stg[k];
        float xb = stg[(4096 - k) & 4095];
        float xc = stg[2048 + k];
        float xd = stg[2048 - k];
        float2 A = ca[k], B = cb[k], C = cc[k], D = cd[k];
        zr[p] = A.x * xa + B.x * xb + C.x * xc + D.x * xd;
        zi[p] = A.y * xa + B.y * xb + C.y * xc + D.y * xd;
    }
    radix8(zr, zi, tr, ti);
    {
        int baseA = 8 * t + (t >> 2);
        b0r[baseA] = tr[0]; b0i[baseA] = ti[0];
#pragma unroll
        for (int q = 1; q < 8; ++q) {
            float2 w = tw2048[(t * q) & 2047];
            b0r[baseA + q] = w.x * tr[q] - w.y * ti[q];
            b0i[baseA + q] = w.x * ti[q] + w.y * tr[q];
        }
    }
    __syncthreads();
    {
        float ar[8], ai[8];
        int rb = t + (t >> 5);
#pragma unroll
        for (int p = 0; p < 8; ++p) { ar[p] = b0r[rb + 264 * p]; ai[p] = b0i[rb + 264 * p]; }
        radix8(ar, ai, tr, ti);
        int j = t >> 3, k = t & 7, wj = 8 * j;
        int baseB = 68 * j + k;
        b1r[baseB] = tr[0]; b1i[baseB] = ti[0];
#pragma unroll
        for (int q = 1; q < 8; ++q) {
            int off = baseB + 8 * q + (q >> 1);
            float2 w = tw2048[(wj * q) & 2047];
            b1r[off] = w.x * tr[q] - w.y * ti[q];
            b1i[off] = w.x * ti[q] + w.y * tr[q];
        }
    }
    __syncthreads();
    {
        float ar[8], ai[8];
        int rb = t + (t >> 4);
#pragma unroll
        for (int p = 0; p < 8; ++p) { ar[p] = b1r[rb + 272 * p]; ai[p] = b1i[rb + 272 * p]; }
        radix8(ar, ai, tr, ti);
        int j = t >> 6, wj = 64 * j, k = t & 63;
        int baseC = 528 * j + k + (k >> 5);
        b0r[baseC] = tr[0]; b0i[baseC] = ti[0];
#pragma unroll
        for (int q = 1; q < 8; ++q) {
            int off = baseC + 66 * q;
            float2 w = tw2048[(wj * q) & 2047];
            b0r[off] = w.x * tr[q] - w.y * ti[q];
            b0i[off] = w.x * ti[q] + w.y * tr[q];
        }
    }
    __syncthreads();
#pragma unroll
    for (int u = 0; u < 2; ++u) {
        int b = t + 256 * u;
        int rb = b + (b >> 5);
        int wb = b + (b >> 4);
        float a0r = b0r[rb], a0i = b0i[rb];
        float a1r = b0r[rb + 528], a1i = b0i[rb + 528];
        float a2r = b0r[rb + 1056], a2i = b0i[rb + 1056];
        float a3r = b0r[rb + 1584], a3i = b0i[rb + 1584];
        float s02r = a0r + a2r, s02i = a0i + a2i;
        float d02r = a0r - a2r, d02i = a0i - a2i;
        float s13r = a1r + a3r, s13i = a1i + a3i;
        float d13r = a1r - a3r, d13i = a1i - a3i;
        b1r[wb] = s02r + s13r;          b1i[wb] = s02i + s13i;
        b1r[wb + 544] = d02r - d13i;    b1i[wb + 544] = d02i + d13r;
        b1r[wb + 1088] = s02r - s13r;   b1i[wb + 1088] = s02i - s13i;
        b1r[wb + 1632] = d02r + d13i;   b1i[wb + 1632] = d02i - d13r;
    }
    __syncthreads();
#pragma unroll
    for (int i = 0; i < 4; ++i) {
        int s = t + 256 * i;
        int l2 = 2047 - s;
        int ms = s + (s >> 4);
        int ml = l2 + (l2 >> 4);
        float4 o = make_float4(b1r[ms], b1i[ml], b1i[ms], b1r[ml]);
        *(float4*)&xr[4 * s] = o;
    }
}

// ---- host-side table construction (once, double precision) ----------------
#define TABLE_BYTES (7 * 16384)   // tw2048 | ca | cb | cc | cd | cAC(32KB)
static void build_tables_host(char* blob) {
    float2* tw2048 = (float2*)blob;
    float2* ca = (float2*)(blob + 1 * 16384);
    float2* cb = (float2*)(blob + 2 * 16384);
    float2* cc = (float2*)(blob + 3 * 16384);
    float2* cd = (float2*)(blob + 4 * 16384);
    float4* cAC = (float4*)(blob + 5 * 16384);
    const double s = 0.5 / 4096.0;
    for (int k = 0; k < 2048; ++k) {
        double aw = M_PI * (double)k / 2048.0;
        double wr = cos(aw), wi = sin(aw);
        double a1 = M_PI * (double)k / 8192.0;
        double e1r = cos(a1), e1i = sin(a1);
        double a2 = M_PI * (double)(k + 2048) / 8192.0;
        double e2r = cos(a2), e2i = sin(a2);
        double Ar = s * ((1.0 - wi) * e1r - wr * e1i);
        double Ai = s * ((1.0 - wi) * e1i + wr * e1r);
        double Br = (k == 0) ? 0.0 : Ai;
        double Bi = (k == 0) ? 0.0 : -Ar;
        double Cr = s * ((1.0 + wi) * e2r + wr * e2i);
        double Ci = s * ((1.0 + wi) * e2i - wr * e2r);
        ca[k] = make_float2((float)Ar, (float)Ai);
        cb[k] = make_float2((float)Br, (float)Bi);
        cc[k] = make_float2((float)Cr, (float)Ci);
        cd[k] = make_float2((float)Ci, (float)-Cr);
        cAC[k] = make_float4((float)Ar, (float)Ai, (float)Cr, (float)Ci);
        double at = M_PI * (double)k / 1024.0;
        tw2048[k] = make_float2((float)cos(at), (float)sin(at));
    }
}

extern "C" void kernel_launch(void* const* d_in, const int* in_sizes, int n_in,
                              void* d_out, int out_size, void* d_ws, size_t ws_size,
                              hipStream_t stream) {
    const float* x = (const float*)d_in[0];
    float* out = (float*)d_out;

    float2* tw2048 = (float2*)d_ws;
    float2* ca = (float2*)((char*)d_ws + 1 * 16384);
    float2* cb = (float2*)((char*)d_ws + 2 * 16384);
    float2* cc = (float2*)((char*)d_ws + 3 * 16384);
    float2* cd = (float2*)((char*)d_ws + 4 * 16384);
    float4* cAC = (float4*)((char*)d_ws + 5 * 16384);   // 32 KB
    float2* T1 = (float2*)((char*)d_ws + (1 << 20));    // 64 MB

    static char* h_tables = nullptr;
    if (!h_tables) {
        h_tables = new char[TABLE_BYTES];
        build_tables_host(h_tables);
    }
    hipMemcpyAsync(d_ws, h_tables, TABLE_BYTES, hipMemcpyHostToDevice, stream);

    col_a_kernel<<<2048, TT, 0, stream>>>(x, cAC, tw2048, T1);
    col_b_kernel<<<1024, TT, 0, stream>>>(T1, out);
    idct_rows_kernel<<<4096, TT, 0, stream>>>(ca, cb, cc, cd, tw2048, out);
}

// Round 13
// 187.438 us; speedup vs baseline: 1.1170x; 1.1170x over previous
//
#include <hip/hip_runtime.h>
#include <math.h>

// 2D IDCT 4096x4096 — THREE kernels, no init kernel, no host memcpy.
// colA: self-sufficient — Z-coeffs + output twiddles computed on the fly
//       via v_sin/v_cos (revolution args are exact binary fractions ->
//       no argument rounding; ~1ulp). Blocks 0-7 additionally write the
//       double-precision tables (tw2048, ca..cd) that the rows pass reads
//       (ready at rows launch by stream ordering). T1 stored [n2][k1][c].
// colB: 64-pt FFT as in-wave DIT over k1; dense 64-consecutive-row reads.
// rows: in-place LDS Stockham radix-8/8/8/4, float4 staged I/O.
// Round-12 lesson: pageable hipMemcpyAsync cost ~20-40us under capture —
// killed. Rounds 9-11: cooperative launch flaky under capture — avoided.

#define TT 256

constexpr float W64R[32] = {
    1.0f, 0.995184726672197f, 0.980785280403230f, 0.956940335732209f,
    0.923879532511287f, 0.881921264348355f, 0.831469612302545f, 0.773010453362737f,
    0.707106781186548f, 0.634393284163645f, 0.555570233019602f, 0.471396736825998f,
    0.382683432365090f, 0.290284677254462f, 0.195090322016128f, 0.0980171403295606f,
    0.0f, -0.0980171403295606f, -0.195090322016128f, -0.290284677254462f,
    -0.382683432365090f, -0.471396736825998f, -0.555570233019602f, -0.634393284163645f,
    -0.707106781186548f, -0.773010453362737f, -0.831469612302545f, -0.881921264348355f,
    -0.923879532511287f, -0.956940335732209f, -0.980785280403230f, -0.995184726672197f};
constexpr float W64I[32] = {
    0.0f, 0.0980171403295606f, 0.195090322016128f, 0.290284677254462f,
    0.382683432365090f, 0.471396736825998f, 0.555570233019602f, 0.634393284163645f,
    0.707106781186548f, 0.773010453362737f, 0.831469612302545f, 0.881921264348355f,
    0.923879532511287f, 0.956940335732209f, 0.980785280403230f, 0.995184726672197f,
    1.0f, 0.995184726672197f, 0.980785280403230f, 0.956940335732209f,
    0.923879532511287f, 0.881921264348355f, 0.831469612302545f, 0.773010453362737f,
    0.707106781186548f, 0.634393284163645f, 0.555570233019602f, 0.471396736825998f,
    0.382683432365090f, 0.290284677254462f, 0.195090322016128f, 0.0980171403295606f};

__device__ __forceinline__ constexpr int brev(int x, int bits) {
    int r = 0;
    for (int i = 0; i < bits; ++i) { r = (r << 1) | (x & 1); x >>= 1; }
    return r;
}

template <int NP>
__device__ __forceinline__ void fft_dif(float* re, float* im) {
#pragma unroll
    for (int h = NP / 2; h >= 1; h >>= 1) {
#pragma unroll
        for (int b = 0; b < NP; b += 2 * h) {
#pragma unroll
            for (int k = 0; k < h; ++k) {
                float ur = re[b + k], ui = im[b + k];
                float vr = re[b + k + h], vi = im[b + k + h];
                float dr = ur - vr, di = ui - vi;
                re[b + k] = ur + vr;
                im[b + k] = ui + vi;
                float wr = W64R[k * (32 / h)], wi = W64I[k * (32 / h)];
                re[b + k + h] = dr * wr - di * wi;
                im[b + k + h] = dr * wi + di * wr;
            }
        }
    }
}

#define C_SQ2 0.70710678118654752440f
__device__ __forceinline__ void radix8(const float* ar, const float* ai,
                                       float* tr, float* ti) {
    float s04r = ar[0] + ar[4], s04i = ai[0] + ai[4];
    float d04r = ar[0] - ar[4], d04i = ai[0] - ai[4];
    float s26r = ar[2] + ar[6], s26i = ai[2] + ai[6];
    float d26r = ar[2] - ar[6], d26i = ai[2] - ai[6];
    float E0r = s04r + s26r, E0i = s04i + s26i;
    float E1r = d04r - d26i, E1i = d04i + d26r;
    float E2r = s04r - s26r, E2i = s04i - s26i;
    float E3r = d04r + d26i, E3i = d04i - d26r;
    float s15r = ar[1] + ar[5], s15i = ai[1] + ai[5];
    float d15r = ar[1] - ar[5], d15i = ai[1] - ai[5];
    float s37r = ar[3] + ar[7], s37i = ai[3] + ai[7];
    float d37r = ar[3] - ar[7], d37i = ai[3] - ai[7];
    float O0r = s15r + s37r, O0i = s15i + s37i;
    float O1r = d15r - d37i, O1i = d15i + d37r;
    float O2r = s15r - s37r, O2i = s15i - s37i;
    float O3r = d15r + d37i, O3i = d15i - d37r;
    float W1r = C_SQ2 * (O1r - O1i), W1i = C_SQ2 * (O1r + O1i);
    float W2r = -O2i, W2i = O2r;
    float W3r = -C_SQ2 * (O3r + O3i), W3i = C_SQ2 * (O3r - O3i);
    tr[0] = E0r + O0r; ti[0] = E0i + O0i;
    tr[4] = E0r - O0r; ti[4] = E0i - O0i;
    tr[1] = E1r + W1r; ti[1] = E1i + W1i;
    tr[5] = E1r - W1r; ti[5] = E1i - W1i;
    tr[2] = E2r + W2r; ti[2] = E2i + W2i;
    tr[6] = E2r - W2r; ti[6] = E2i - W2i;
    tr[3] = E3r + W3r; ti[3] = E3i + W3i;
    tr[7] = E3r - W3r; ti[7] = E3i - W3i;
}

// ---- column pass A: self-sufficient, on-the-fly coefficients --------------
// grid 2048 x 256: vb -> bx (c-tile, &127), by (>>7); k1 = by*4 + (t>>6).
// Lanes l / l+32: same column, even/odd k2 parity; 16-pt reg FFT per half,
// __shfl_xor(32) DIT combine. All trig: v_sin/v_cos with EXACT revolution
// arguments (k/4096, k/16384, k1*n2/2048). Blocks 0-7: side-write the
// double-precision tables for the rows pass.
__global__ __launch_bounds__(TT) void col_a_kernel(
    const float* __restrict__ x,
    float2* __restrict__ tw2048,
    float2* __restrict__ ca, float2* __restrict__ cb,
    float2* __restrict__ cc, float2* __restrict__ cd,
    float2* __restrict__ T1) {
    const int vb = blockIdx.x;
    const int t = threadIdx.x;

    if (vb < 8) {   // side job: tables for the rows pass (double precision)
        int k = vb * TT + t;
        const double s = 0.5 / 4096.0;
        double aw = M_PI * (double)k / 2048.0;
        double wr = cos(aw), wi = sin(aw);
        double a1 = M_PI * (double)k / 8192.0;
        double e1r = cos(a1), e1i = sin(a1);
        double a2 = M_PI * (double)(k + 2048) / 8192.0;
        double e2r = cos(a2), e2i = sin(a2);
        double Ar = s * ((1.0 - wi) * e1r - wr * e1i);
        double Ai = s * ((1.0 - wi) * e1i + wr * e1r);
        double Br = (k == 0) ? 0.0 : Ai;
        double Bi = (k == 0) ? 0.0 : -Ar;
        double Cr = s * ((1.0 + wi) * e2r + wr * e2i);
        double Ci = s * ((1.0 + wi) * e2i - wr * e2r);
        ca[k] = make_float2((float)Ar, (float)Ai);
        cb[k] = make_float2((float)Br, (float)Bi);
        cc[k] = make_float2((float)Cr, (float)Ci);
        cd[k] = make_float2((float)Ci, (float)-Cr);
        double at = M_PI * (double)k / 1024.0;
        tw2048[k] = make_float2((float)cos(at), (float)sin(at));
    }

    const int bx = vb & 127, by = vb >> 7;
    const int l = t & 63;
    const int ty = t >> 6;
    const int par = l >> 5;                  // k2 parity of this lane
    const int c = bx * 32 + (l & 31);
    const int k1 = by * 4 + ty;              // [0,64)
    const float S = 0.5f / 4096.0f;
    float fr[16], fi[16];
#pragma unroll
    for (int a = 0; a < 16; ++a) {
        int k = k1 + 64 * (2 * a + par);
        float xa = x[(size_t)k * 4096 + c];
        float xb = x[(size_t)((4096 - k) & 4095) * 4096 + c];
        float xc = x[(size_t)(2048 + k) * 4096 + c];
        float xd = x[(size_t)(2048 - k) * 4096 + c];
        // coefficients on the fly; revolution args are exact fp32 fractions
        float rw = (float)k * (1.0f / 4096.0f);      // angle pi*k/2048
        float wr = __builtin_amdgcn_cosf(rw);
        float wi = __builtin_amdgcn_sinf(rw);
        float r1 = (float)k * (1.0f / 16384.0f);     // angle pi*k/8192
        float e1r = __builtin_amdgcn_cosf(r1);
        float e1i = __builtin_amdgcn_sinf(r1);
        float e2r = C_SQ2 * (e1r - e1i);             // e2 = e1 * e^{i pi/4}
        float e2i = C_SQ2 * (e1r + e1i);
        float omw = 1.0f - wi, opw = 1.0f + wi;
        float Ar = S * (omw * e1r - wr * e1i);
        float Ai = S * (omw * e1i + wr * e1r);
        float Cr = S * (opw * e2r + wr * e2i);
        float Ci = S * (opw * e2i - wr * e2r);
        float bs = (k == 0) ? 0.0f : 1.0f;           // B=(Ai,-Ar), D=(Ci,-Cr)
        fr[a] = Ar * xa + bs * Ai * xb + Cr * xc + Ci * xd;
        fi[a] = Ai * xa - bs * Ar * xb + Ci * xc - Cr * xd;
    }
    fft_dif<16>(fr, fi);                     // E (par=0) or O (par=1)
    const float sgn = par ? -1.0f : 1.0f;
#pragma unroll
    for (int j = 0; j < 16; ++j) {
        int n = brev(j, 4);
        float wr = par ? W64R[2 * n] : 1.0f; // W32^n on odd branch
        float wi = par ? W64I[2 * n] : 0.0f;
        float vr = fr[j] * wr - fi[j] * wi;
        float vi = fr[j] * wi + fi[j] * wr;
        float orr = __shfl_xor(vr, 32, 64);
        float oii = __shfl_xor(vi, 32, 64);
        float zr = orr + sgn * vr;           // lower: E+WO ; upper: E-WO
        float zi = oii + sgn * vi;
        int n2 = par ? (n + 16) : n;
        float rv = (float)(k1 * n2) * (1.0f / 2048.0f);  // < 1953/2048, exact
        float twr = __builtin_amdgcn_cosf(rv);
        float twi = __builtin_amdgcn_sinf(rv);
        float2 o = make_float2(zr * twr - zi * twi,
                               zr * twi + zi * twr);
        T1[(size_t)(n2 * 64 + k1) * 4096 + c] = o;   // [n2][k1][c]
    }
}

// ---- column pass B: 64-pt FFT as in-wave DIT over k1 ----------------------
// T1 [n2][k1][c]: block reads 64 CONSECUTIVE rows (1 MB window, dense).
// grid 1024 x 256: vb -> bx (&127), by (>>7); n2 = by*4 + (t>>6).
__global__ __launch_bounds__(TT, 1) void col_b_kernel(
    const float2* __restrict__ T1, float* __restrict__ out) {
    const int vb = blockIdx.x;
    const int bx = vb & 127, by = vb >> 7;
    const int t = threadIdx.x;
    const int wv = t >> 6;
    const int l = t & 63;
    const int par = l >> 5;                  // k1 parity of this lane
    const int c = bx * 32 + (l & 31);
    const int n2 = by * 4 + wv;
    float fr[32], fi[32];
#pragma unroll
    for (int a = 0; a < 32; ++a) {
        int k1 = 2 * a + par;
        float2 v = T1[(size_t)(n2 * 64 + k1) * 4096 + c];
        fr[a] = v.x; fi[a] = v.y;
    }
    fft_dif<32>(fr, fi);                     // E (par=0) or O (par=1)
    const float sgn = par ? -1.0f : 1.0f;
#pragma unroll
    for (int j = 0; j < 32; ++j) {
        int n = brev(j, 5);
        float wr = par ? W64R[n] : 1.0f;     // W64^n on odd branch
        float wi = par ? W64I[n] : 0.0f;
        float vr = fr[j] * wr - fi[j] * wi;
        float vi = fr[j] * wi + fi[j] * wr;
        float orr = __shfl_xor(vr, 32, 64);
        float oii = __shfl_xor(vi, 32, 64);
        float zr = orr + sgn * vr;
        float zi = oii + sgn * vi;
        int n1 = par ? (n + 32) : n;
        int m = 32 * n1 + n2;
        int r_re = (n1 < 32) ? 4 * m     : 8191 - 4 * m;
        int r_im = (n1 < 32) ? 4 * m + 2 : 8189 - 4 * m;
        out[(size_t)r_re * 4096 + c] = zr;
        out[(size_t)r_im * 4096 + c] = zi;
    }
}

// ---- row pass: in-place per-row IDCT, float4 staged I/O -------------------
__global__ __launch_bounds__(TT) void idct_rows_kernel(
    const float2* __restrict__ ca, const float2* __restrict__ cb,
    const float2* __restrict__ cc, const float2* __restrict__ cd,
    const float2* __restrict__ tw2048, float* __restrict__ io) {
    __shared__ float pool[8576];
    float* b0r = pool;
    float* b0i = pool + 2112;
    float* b1r = pool + 4224;
    float* b1i = pool + 6400;
    float* stg = pool + 4224;   // overlays b1 (free until stage B)
    const int t = threadIdx.x;
    float* __restrict__ xr = io + (size_t)blockIdx.x * 4096;

#pragma unroll
    for (int u = 0; u < 4; ++u) {
        int idx = t + 256 * u;
        float4 v = ((const float4*)xr)[idx];
        *(float4*)&stg[4 * idx] = v;
    }
    __syncthreads();

    float zr[8], zi[8], tr[8], ti[8];
#pragma unroll
    for (int p = 0; p < 8; ++p) {
        int k = t + 256 * p;
        float xa = stg[k];
        float xb = stg[(4096 - k) & 4095];
        float xc = stg[2048 + k];
        float xd = stg[2048 - k];
        float2 A = ca[k], B = cb[k], C = cc[k], D = cd[k];
        zr[p] = A.x * xa + B.x * xb + C.x * xc + D.x * xd;
        zi[p] = A.y * xa + B.y * xb + C.y * xc + D.y * xd;
    }
    radix8(zr, zi, tr, ti);
    {
        int baseA = 8 * t + (t >> 2);
        b0r[baseA] = tr[0]; b0i[baseA] = ti[0];
#pragma unroll
        for (int q = 1; q < 8; ++q) {
            float2 w = tw2048[(t * q) & 2047];
            b0r[baseA + q] = w.x * tr[q] - w.y * ti[q];
            b0i[baseA + q] = w.x * ti[q] + w.y * tr[q];
        }
    }
    __syncthreads();
    {
        float ar[8], ai[8];
        int rb = t + (t >> 5);
#pragma unroll
        for (int p = 0; p < 8; ++p) { ar[p] = b0r[rb + 264 * p]; ai[p] = b0i[rb + 264 * p]; }
        radix8(ar, ai, tr, ti);
        int j = t >> 3, k = t & 7, wj = 8 * j;
        int baseB = 68 * j + k;
        b1r[baseB] = tr[0]; b1i[baseB] = ti[0];
#pragma unroll
        for (int q = 1; q < 8; ++q) {
            int off = baseB + 8 * q + (q >> 1);
            float2 w = tw2048[(wj * q) & 2047];
            b1r[off] = w.x * tr[q] - w.y * ti[q];
            b1i[off] = w.x * ti[q] + w.y * tr[q];
        }
    }
    __syncthreads();
    {
        float ar[8], ai[8];
        int rb = t + (t >> 4);
#pragma unroll
        for (int p = 0; p < 8; ++p) { ar[p] = b1r[rb + 272 * p]; ai[p] = b1i[rb + 272 * p]; }
        radix8(ar, ai, tr, ti);
        int j = t >> 6, wj = 64 * j, k = t & 63;
        int baseC = 528 * j + k + (k >> 5);
        b0r[baseC] = tr[0]; b0i[baseC] = ti[0];
#pragma unroll
        for (int q = 1; q < 8; ++q) {
            int off = baseC + 66 * q;
            float2 w = tw2048[(wj * q) & 2047];
            b0r[off] = w.x * tr[q] - w.y * ti[q];
            b0i[off] = w.x * ti[q] + w.y * tr[q];
        }
    }
    __syncthreads();
#pragma unroll
    for (int u = 0; u < 2; ++u) {
        int b = t + 256 * u;
        int rb = b + (b >> 5);
        int wb = b + (b >> 4);
        float a0r = b0r[rb], a0i = b0i[rb];
        float a1r = b0r[rb + 528], a1i = b0i[rb + 528];
        float a2r = b0r[rb + 1056], a2i = b0i[rb + 1056];
        float a3r = b0r[rb + 1584], a3i = b0i[rb + 1584];
        float s02r = a0r + a2r, s02i = a0i + a2i;
        float d02r = a0r - a2r, d02i = a0i - a2i;
        float s13r = a1r + a3r, s13i = a1i + a3i;
        float d13r = a1r - a3r, d13i = a1i - a3i;
        b1r[wb] = s02r + s13r;          b1i[wb] = s02i + s13i;
        b1r[wb + 544] = d02r - d13i;    b1i[wb + 544] = d02i + d13r;
        b1r[wb + 1088] = s02r - s13r;   b1i[wb + 1088] = s02i - s13i;
        b1r[wb + 1632] = d02r + d13i;   b1i[wb + 1632] = d02i - d13r;
    }
    __syncthreads();
#pragma unroll
    for (int i = 0; i < 4; ++i) {
        int s = t + 256 * i;
        int l2 = 2047 - s;
        int ms = s + (s >> 4);
        int ml = l2 + (l2 >> 4);
        float4 o = make_float4(b1r[ms], b1i[ml], b1i[ms], b1r[ml]);
        *(float4*)&xr[4 * s] = o;
    }
}

extern "C" void kernel_launch(void* const* d_in, const int* in_sizes, int n_in,
                              void* d_out, int out_size, void* d_ws, size_t ws_size,
                              hipStream_t stream) {
    const float* x = (const float*)d_in[0];
    float* out = (float*)d_out;

    float2* tw2048 = (float2*)d_ws;
    float2* ca = (float2*)((char*)d_ws + 1 * 16384);
    float2* cb = (float2*)((char*)d_ws + 2 * 16384);
    float2* cc = (float2*)((char*)d_ws + 3 * 16384);
    float2* cd = (float2*)((char*)d_ws + 4 * 16384);
    float2* T1 = (float2*)((char*)d_ws + (1 << 20));    // 64 MB

    col_a_kernel<<<2048, TT, 0, stream>>>(x, tw2048, ca, cb, cc, cd, T1);
    col_b_kernel<<<1024, TT, 0, stream>>>(T1, out);
    idct_rows_kernel<<<4096, TT, 0, stream>>>(ca, cb, cc, cd, tw2048, out);
}

// Round 14
// 186.222 us; speedup vs baseline: 1.1243x; 1.0065x over previous
//
#include <hip/hip_runtime.h>
#include <math.h>

// 2D IDCT 4096x4096 — THREE kernels.
// colA: self-sufficient — Z-coeffs + output twiddles via v_sin/v_cos
//       (revolution args exact -> ~1ulp; verified absmax unchanged r13).
//       Blocks 0-7 side-write the double tables the rows pass reads.
// colB: 64-pt FFT as in-wave DIT over k1; dense 64-consecutive-row reads.
// rows: SINGLE-buffer LDS Stockham (16.9 KB, was 34.3 KB double-buffer):
//       each stage reads-all->sync->writes-in-place; stage D is
//       per-thread-private (no internal sync). 2x resident blocks/CU to
//       fill the barrier-chain bubbles (rows was 42us vs 20us BW floor
//       at 25% occupancy).

#define TT 256

constexpr float W64R[32] = {
    1.0f, 0.995184726672197f, 0.980785280403230f, 0.956940335732209f,
    0.923879532511287f, 0.881921264348355f, 0.831469612302545f, 0.773010453362737f,
    0.707106781186548f, 0.634393284163645f, 0.555570233019602f, 0.471396736825998f,
    0.382683432365090f, 0.290284677254462f, 0.195090322016128f, 0.0980171403295606f,
    0.0f, -0.0980171403295606f, -0.195090322016128f, -0.290284677254462f,
    -0.382683432365090f, -0.471396736825998f, -0.555570233019602f, -0.634393284163645f,
    -0.707106781186548f, -0.773010453362737f, -0.831469612302545f, -0.881921264348355f,
    -0.923879532511287f, -0.956940335732209f, -0.980785280403230f, -0.995184726672197f};
constexpr float W64I[32] = {
    0.0f, 0.0980171403295606f, 0.195090322016128f, 0.290284677254462f,
    0.382683432365090f, 0.471396736825998f, 0.555570233019602f, 0.634393284163645f,
    0.707106781186548f, 0.773010453362737f, 0.831469612302545f, 0.881921264348355f,
    0.923879532511287f, 0.956940335732209f, 0.980785280403230f, 0.995184726672197f,
    1.0f, 0.995184726672197f, 0.980785280403230f, 0.956940335732209f,
    0.923879532511287f, 0.881921264348355f, 0.831469612302545f, 0.773010453362737f,
    0.707106781186548f, 0.634393284163645f, 0.555570233019602f, 0.471396736825998f,
    0.382683432365090f, 0.290284677254462f, 0.195090322016128f, 0.0980171403295606f};

__device__ __forceinline__ constexpr int brev(int x, int bits) {
    int r = 0;
    for (int i = 0; i < bits; ++i) { r = (r << 1) | (x & 1); x >>= 1; }
    return r;
}

template <int NP>
__device__ __forceinline__ void fft_dif(float* re, float* im) {
#pragma unroll
    for (int h = NP / 2; h >= 1; h >>= 1) {
#pragma unroll
        for (int b = 0; b < NP; b += 2 * h) {
#pragma unroll
            for (int k = 0; k < h; ++k) {
                float ur = re[b + k], ui = im[b + k];
                float vr = re[b + k + h], vi = im[b + k + h];
                float dr = ur - vr, di = ui - vi;
                re[b + k] = ur + vr;
                im[b + k] = ui + vi;
                float wr = W64R[k * (32 / h)], wi = W64I[k * (32 / h)];
                re[b + k + h] = dr * wr - di * wi;
                im[b + k + h] = dr * wi + di * wr;
            }
        }
    }
}

#define C_SQ2 0.70710678118654752440f
__device__ __forceinline__ void radix8(const float* ar, const float* ai,
                                       float* tr, float* ti) {
    float s04r = ar[0] + ar[4], s04i = ai[0] + ai[4];
    float d04r = ar[0] - ar[4], d04i = ai[0] - ai[4];
    float s26r = ar[2] + ar[6], s26i = ai[2] + ai[6];
    float d26r = ar[2] - ar[6], d26i = ai[2] - ai[6];
    float E0r = s04r + s26r, E0i = s04i + s26i;
    float E1r = d04r - d26i, E1i = d04i + d26r;
    float E2r = s04r - s26r, E2i = s04i - s26i;
    float E3r = d04r + d26i, E3i = d04i - d26r;
    float s15r = ar[1] + ar[5], s15i = ai[1] + ai[5];
    float d15r = ar[1] - ar[5], d15i = ai[1] - ai[5];
    float s37r = ar[3] + ar[7], s37i = ai[3] + ai[7];
    float d37r = ar[3] - ar[7], d37i = ai[3] - ai[7];
    float O0r = s15r + s37r, O0i = s15i + s37i;
    float O1r = d15r - d37i, O1i = d15i + d37r;
    float O2r = s15r - s37r, O2i = s15i - s37i;
    float O3r = d15r + d37i, O3i = d15i - d37r;
    float W1r = C_SQ2 * (O1r - O1i), W1i = C_SQ2 * (O1r + O1i);
    float W2r = -O2i, W2i = O2r;
    float W3r = -C_SQ2 * (O3r + O3i), W3i = C_SQ2 * (O3r - O3i);
    tr[0] = E0r + O0r; ti[0] = E0i + O0i;
    tr[4] = E0r - O0r; ti[4] = E0i - O0i;
    tr[1] = E1r + W1r; ti[1] = E1i + W1i;
    tr[5] = E1r - W1r; ti[5] = E1i - W1i;
    tr[2] = E2r + W2r; ti[2] = E2i + W2i;
    tr[6] = E2r - W2r; ti[6] = E2i - W2i;
    tr[3] = E3r + W3r; ti[3] = E3i + W3i;
    tr[7] = E3r - W3r; ti[7] = E3i - W3i;
}

// ---- column pass A: self-sufficient, on-the-fly coefficients --------------
// grid 2048 x 256: vb -> bx (c-tile, &127), by (>>7); k1 = by*4 + (t>>6).
__global__ __launch_bounds__(TT) void col_a_kernel(
    const float* __restrict__ x,
    float2* __restrict__ tw2048,
    float2* __restrict__ ca, float2* __restrict__ cb,
    float2* __restrict__ cc, float2* __restrict__ cd,
    float2* __restrict__ T1) {
    const int vb = blockIdx.x;
    const int t = threadIdx.x;

    if (vb < 8) {   // side job: tables for the rows pass (double precision)
        int k = vb * TT + t;
        const double s = 0.5 / 4096.0;
        double aw = M_PI * (double)k / 2048.0;
        double wr = cos(aw), wi = sin(aw);
        double a1 = M_PI * (double)k / 8192.0;
        double e1r = cos(a1), e1i = sin(a1);
        double a2 = M_PI * (double)(k + 2048) / 8192.0;
        double e2r = cos(a2), e2i = sin(a2);
        double Ar = s * ((1.0 - wi) * e1r - wr * e1i);
        double Ai = s * ((1.0 - wi) * e1i + wr * e1r);
        double Br = (k == 0) ? 0.0 : Ai;
        double Bi = (k == 0) ? 0.0 : -Ar;
        double Cr = s * ((1.0 + wi) * e2r + wr * e2i);
        double Ci = s * ((1.0 + wi) * e2i - wr * e2r);
        ca[k] = make_float2((float)Ar, (float)Ai);
        cb[k] = make_float2((float)Br, (float)Bi);
        cc[k] = make_float2((float)Cr, (float)Ci);
        cd[k] = make_float2((float)Ci, (float)-Cr);
        double at = M_PI * (double)k / 1024.0;
        tw2048[k] = make_float2((float)cos(at), (float)sin(at));
    }

    const int bx = vb & 127, by = vb >> 7;
    const int l = t & 63;
    const int ty = t >> 6;
    const int par = l >> 5;                  // k2 parity of this lane
    const int c = bx * 32 + (l & 31);
    const int k1 = by * 4 + ty;              // [0,64)
    const float S = 0.5f / 4096.0f;
    float fr[16], fi[16];
#pragma unroll
    for (int a = 0; a < 16; ++a) {
        int k = k1 + 64 * (2 * a + par);
        float xa = x[(size_t)k * 4096 + c];
        float xb = x[(size_t)((4096 - k) & 4095) * 4096 + c];
        float xc = x[(size_t)(2048 + k) * 4096 + c];
        float xd = x[(size_t)(2048 - k) * 4096 + c];
        // coefficients on the fly; revolution args are exact fp32 fractions
        float rw = (float)k * (1.0f / 4096.0f);      // angle pi*k/2048
        float wr = __builtin_amdgcn_cosf(rw);
        float wi = __builtin_amdgcn_sinf(rw);
        float r1 = (float)k * (1.0f / 16384.0f);     // angle pi*k/8192
        float e1r = __builtin_amdgcn_cosf(r1);
        float e1i = __builtin_amdgcn_sinf(r1);
        float e2r = C_SQ2 * (e1r - e1i);             // e2 = e1 * e^{i pi/4}
        float e2i = C_SQ2 * (e1r + e1i);
        float omw = 1.0f - wi, opw = 1.0f + wi;
        float Ar = S * (omw * e1r - wr * e1i);
        float Ai = S * (omw * e1i + wr * e1r);
        float Cr = S * (opw * e2r + wr * e2i);
        float Ci = S * (opw * e2i - wr * e2r);
        float bs = (k == 0) ? 0.0f : 1.0f;           // B=(Ai,-Ar), D=(Ci,-Cr)
        fr[a] = Ar * xa + bs * Ai * xb + Cr * xc + Ci * xd;
        fi[a] = Ai * xa - bs * Ar * xb + Ci * xc - Cr * xd;
    }
    fft_dif<16>(fr, fi);                     // E (par=0) or O (par=1)
    const float sgn = par ? -1.0f : 1.0f;
#pragma unroll
    for (int j = 0; j < 16; ++j) {
        int n = brev(j, 4);
        float wr = par ? W64R[2 * n] : 1.0f; // W32^n on odd branch
        float wi = par ? W64I[2 * n] : 0.0f;
        float vr = fr[j] * wr - fi[j] * wi;
        float vi = fr[j] * wi + fi[j] * wr;
        float orr = __shfl_xor(vr, 32, 64);
        float oii = __shfl_xor(vi, 32, 64);
        float zr = orr + sgn * vr;           // lower: E+WO ; upper: E-WO
        float zi = oii + sgn * vi;
        int n2 = par ? (n + 16) : n;
        float rv = (float)(k1 * n2) * (1.0f / 2048.0f);  // < 1953/2048, exact
        float twr = __builtin_amdgcn_cosf(rv);
        float twi = __builtin_amdgcn_sinf(rv);
        float2 o = make_float2(zr * twr - zi * twi,
                               zr * twi + zi * twr);
        T1[(size_t)(n2 * 64 + k1) * 4096 + c] = o;   // [n2][k1][c]
    }
}

// ---- column pass B: 64-pt FFT as in-wave DIT over k1 ----------------------
// T1 [n2][k1][c]: block reads 64 CONSECUTIVE rows (1 MB window, dense).
// grid 1024 x 256: vb -> bx (&127), by (>>7); n2 = by*4 + (t>>6).
__global__ __launch_bounds__(TT, 1) void col_b_kernel(
    const float2* __restrict__ T1, float* __restrict__ out) {
    const int vb = blockIdx.x;
    const int bx = vb & 127, by = vb >> 7;
    const int t = threadIdx.x;
    const int wv = t >> 6;
    const int l = t & 63;
    const int par = l >> 5;                  // k1 parity of this lane
    const int c = bx * 32 + (l & 31);
    const int n2 = by * 4 + wv;
    float fr[32], fi[32];
#pragma unroll
    for (int a = 0; a < 32; ++a) {
        int k1 = 2 * a + par;
        float2 v = T1[(size_t)(n2 * 64 + k1) * 4096 + c];
        fr[a] = v.x; fi[a] = v.y;
    }
    fft_dif<32>(fr, fi);                     // E (par=0) or O (par=1)
    const float sgn = par ? -1.0f : 1.0f;
#pragma unroll
    for (int j = 0; j < 32; ++j) {
        int n = brev(j, 5);
        float wr = par ? W64R[n] : 1.0f;     // W64^n on odd branch
        float wi = par ? W64I[n] : 0.0f;
        float vr = fr[j] * wr - fi[j] * wi;
        float vi = fr[j] * wi + fi[j] * wr;
        float orr = __shfl_xor(vr, 32, 64);
        float oii = __shfl_xor(vi, 32, 64);
        float zr = orr + sgn * vr;
        float zi = oii + sgn * vi;
        int n1 = par ? (n + 32) : n;
        int m = 32 * n1 + n2;
        int r_re = (n1 < 32) ? 4 * m     : 8191 - 4 * m;
        int r_im = (n1 < 32) ? 4 * m + 2 : 8189 - 4 * m;
        out[(size_t)r_re * 4096 + c] = zr;
        out[(size_t)r_im * 4096 + c] = zi;
    }
}

// ---- row pass: single-LDS-buffer Stockham (16.9 KB) -----------------------
// bb (complex, phys = L + (L>>5), 2112 floats/component); each stage:
// read-all -> sync -> write-in-place. Stage D butterflies are per-thread-
// private (read set == write set, disjoint across threads): no inner sync.
// Logical index maps identical to the proven double-buffer kernel.
__global__ __launch_bounds__(TT) void idct_rows_kernel(
    const float2* __restrict__ ca, const float2* __restrict__ cb,
    const float2* __restrict__ cc, const float2* __restrict__ cd,
    const float2* __restrict__ tw2048, float* __restrict__ io) {
    __shared__ float pool[4224];
    float* bbr = pool;
    float* bbi = pool + 2112;
    float* stg = pool;            // 4096 floats, overlays bb (disjoint life)
    const int t = threadIdx.x;
    float* __restrict__ xr = io + (size_t)blockIdx.x * 4096;
#define PHI(L) ((L) + ((L) >> 5))

    // stage the row via float4 loads
#pragma unroll
    for (int u = 0; u < 4; ++u) {
        int idx = t + 256 * u;
        float4 v = ((const float4*)xr)[idx];
        *(float4*)&stg[4 * idx] = v;
    }
    __syncthreads();

    float zr[8], zi[8], tr[8], ti[8];
#pragma unroll
    for (int p = 0; p < 8; ++p) {
        int k = t + 256 * p;
        float xa = stg[k];
        float xb = stg[(4096 - k) & 4095];
        float xc = stg[2048 + k];
        float xd = stg[2048 - k];
        float2 A = ca[k], B = cb[k], C = cc[k], D = cd[k];
        zr[p] = A.x * xa + B.x * xb + C.x * xc + D.x * xd;
        zi[p] = A.y * xa + B.y * xb + C.y * xc + D.y * xd;
    }
    __syncthreads();              // all stg reads done; bb region now free
    // stage A: m=1; write L = 8t+q
    radix8(zr, zi, tr, ti);
    {
        int L0 = 8 * t;
        bbr[PHI(L0)] = tr[0]; bbi[PHI(L0)] = ti[0];
#pragma unroll
        for (int q = 1; q < 8; ++q) {
            float2 w = tw2048[(t * q) & 2047];
            bbr[PHI(L0 + q)] = w.x * tr[q] - w.y * ti[q];
            bbi[PHI(L0 + q)] = w.x * ti[q] + w.y * tr[q];
        }
    }
    __syncthreads();
    // stage B: m=8; read L = t+256p, write L = 64j+8q+k
    {
        float ar[8], ai[8];
#pragma unroll
        for (int p = 0; p < 8; ++p) {
            int L = t + 256 * p;
            ar[p] = bbr[PHI(L)]; ai[p] = bbi[PHI(L)];
        }
        __syncthreads();
        radix8(ar, ai, tr, ti);
        int j = t >> 3, k = t & 7, wj = 8 * j;
        int Lb = 64 * j + k;
        bbr[PHI(Lb)] = tr[0]; bbi[PHI(Lb)] = ti[0];
#pragma unroll
        for (int q = 1; q < 8; ++q) {
            int L = Lb + 8 * q;
            float2 w = tw2048[(wj * q) & 2047];
            bbr[PHI(L)] = w.x * tr[q] - w.y * ti[q];
            bbi[PHI(L)] = w.x * ti[q] + w.y * tr[q];
        }
        __syncthreads();
    }
    // stage C: m=64; read L = t+256p, write L = 512j+64q+k
    {
        float ar[8], ai[8];
#pragma unroll
        for (int p = 0; p < 8; ++p) {
            int L = t + 256 * p;
            ar[p] = bbr[PHI(L)]; ai[p] = bbi[PHI(L)];
        }
        __syncthreads();
        radix8(ar, ai, tr, ti);
        int j = t >> 6, wj = 64 * j, k = t & 63;
        int Lb = 512 * j + k;
        bbr[PHI(Lb)] = tr[0]; bbi[PHI(Lb)] = ti[0];
#pragma unroll
        for (int q = 1; q < 8; ++q) {
            int L = Lb + 64 * q;
            float2 w = tw2048[(wj * q) & 2047];
            bbr[PHI(L)] = w.x * tr[q] - w.y * ti[q];
            bbi[PHI(L)] = w.x * ti[q] + w.y * tr[q];
        }
        __syncthreads();
    }
    // stage D: m=512 radix-4, tw=1; in-place, per-thread-private butterflies
#pragma unroll
    for (int u = 0; u < 2; ++u) {
        int b = t + 256 * u;
        float a0r = bbr[PHI(b)],        a0i = bbi[PHI(b)];
        float a1r = bbr[PHI(b + 512)],  a1i = bbi[PHI(b + 512)];
        float a2r = bbr[PHI(b + 1024)], a2i = bbi[PHI(b + 1024)];
        float a3r = bbr[PHI(b + 1536)], a3i = bbi[PHI(b + 1536)];
        float s02r = a0r + a2r, s02i = a0i + a2i;
        float d02r = a0r - a2r, d02i = a0i - a2i;
        float s13r = a1r + a3r, s13i = a1i + a3i;
        float d13r = a1r - a3r, d13i = a1i - a3i;
        bbr[PHI(b)]        = s02r + s13r;  bbi[PHI(b)]        = s02i + s13i;
        bbr[PHI(b + 512)]  = d02r - d13i;  bbi[PHI(b + 512)]  = d02i + d13r;
        bbr[PHI(b + 1024)] = s02r - s13r;  bbi[PHI(b + 1024)] = s02i - s13i;
        bbr[PHI(b + 1536)] = d02r + d13i;  bbi[PHI(b + 1536)] = d02i - d13r;
    }
    __syncthreads();
    // epilogue: out[4s..] = {Re z[s], Im z[2047-s], Im z[s], Re z[2047-s]}
#pragma unroll
    for (int i = 0; i < 4; ++i) {
        int s = t + 256 * i;
        int l2 = 2047 - s;
        float4 o = make_float4(bbr[PHI(s)], bbi[PHI(l2)],
                               bbi[PHI(s)], bbr[PHI(l2)]);
        *(float4*)&xr[4 * s] = o;
    }
#undef PHI
}

extern "C" void kernel_launch(void* const* d_in, const int* in_sizes, int n_in,
                              void* d_out, int out_size, void* d_ws, size_t ws_size,
                              hipStream_t stream) {
    const float* x = (const float*)d_in[0];
    float* out = (float*)d_out;

    float2* tw2048 = (float2*)d_ws;
    float2* ca = (float2*)((char*)d_ws + 1 * 16384);
    float2* cb = (float2*)((char*)d_ws + 2 * 16384);
    float2* cc = (float2*)((char*)d_ws + 3 * 16384);
    float2* cd = (float2*)((char*)d_ws + 4 * 16384);
    float2* T1 = (float2*)((char*)d_ws + (1 << 20));    // 64 MB

    col_a_kernel<<<2048, TT, 0, stream>>>(x, tw2048, ca, cb, cc, cd, T1);
    col_b_kernel<<<1024, TT, 0, stream>>>(T1, out);
    idct_rows_kernel<<<4096, TT, 0, stream>>>(ca, cb, cc, cd, tw2048, out);
}